// Round 6
// baseline (143.673 us; speedup 1.0000x reference)
//
#include <hip/hip_runtime.h>
#include <hip/hip_bf16.h>

// SConv: x(8,64,128,128) f32, Coefficient(9,9), W(128,64,3,3), b(128)
// out[b,co,h,w] = sum_{c,t} z[b,c,h,w][t] * W[co,c,t] + b[co]
// z = [sorted8(y[noncenter])[0:4], center, sorted8[4:8]],
// y_i = sum_j Coefficient[i,j] * patch_j (3x3 neighborhood, zero pad 1).
//
// Round 13 == Round 12 resubmit (R12 bench was an infra failure: container
// died twice; no counters). Rationale recap (vs R11 61.4 us / 6.3M bank
// conflicts):
//  - k-space REPERMUTED (we own the W repack, any k bijection is legal):
//    k' = rho(c)*8 + t (t<8), k' = 512 + c (t=8), rho(c)=((c&7)<<3)|(c>>3).
//    Each thread's 8 z-values per row = ONE aligned ds_write_b128 (+1 b16).
//    40 store instrs/thread -> 16; parity branch GONE.
//  - With c = wave+8j: rho(c) = 8*wave+j -> store granule-quad = (row+j)%8,
//    8 lanes per quad -> conflict-free b128 stores.
//  - SROW 600 -> 584 (1168 B = 73 granules, 73%8=1): quad(row)=row%8 ->
//    conflict-free b128 reads, NO swizzle/XOR anywhere.
// LDS 64 x 1168 B = 74752 B -> 2 blocks/CU. MFMA 32x32x16.
// Layouts: A row=lane&31, k=(lane>>5)*8+e; C/D col=lane&31=co,
// row=(reg&3)+8*(reg>>2)+4*(lane>>5) (m74/m101).

#define B_   8
#define C_   64
#define H_   128
#define W_   128
#define CO_  128
#define K_   576    // C_*9 = 36*16
#define MT   64     // sites per block (4h x 16w)
#define SROW 584    // LDS row stride in elements (1168 B = 73 granules)

typedef __attribute__((ext_vector_type(8)))  short  short8;
typedef __attribute__((ext_vector_type(8)))  __bf16 bf16x8;
typedef __attribute__((ext_vector_type(16))) float  f32x16;
typedef __attribute__((ext_vector_type(2)))  float  f32x2;

__device__ __forceinline__ void cswap2(f32x2 &a, f32x2 &b) {
    f32x2 lo = __builtin_elementwise_min(a, b);
    f32x2 hi = __builtin_elementwise_max(a, b);
    a = lo; b = hi;
}

__device__ __forceinline__ ushort f2bf(float f) {
    union { float f; unsigned u; } v; v.f = f;
    unsigned r = v.u + 0x7fffu + ((v.u >> 16) & 1u);  // RNE
    return (ushort)(r >> 16);
}

__device__ __forceinline__ unsigned pack2bf(float lo, float hi) {
    union { __hip_bfloat162 h; unsigned u; } cv;
    cv.h = __float22bfloat162_rn(make_float2(lo, hi));  // x->low word
    return cv.u;
}

// Repack W[co][c*9+t] f32 -> Wb[((nt*36+ks)*64+lane)*8+e] bf16 where
// co = nt*32+(lane&31), k' = ks*16+(lane>>5)*8+e, and k' decodes as:
//   k' < 512:  rc = k'>>3, t = k'&7, c = ((rc&7)<<3)|(rc>>3)   (rho inverse)
//   k' >= 512: c = k'-512, t = 8
// One contiguous 1 KB line per (nt,ks) = exactly one wave-fragment.
__global__ __launch_bounds__(256) void conv_W_bf16(const float* __restrict__ Wg,
                                                   ushort* __restrict__ Wb) {
    int i = blockIdx.x * 256 + threadIdx.x;
    if (i >= CO_ * K_) return;
    const int e    = i & 7;
    const int lane = (i >> 3) & 63;
    const int t9   = i >> 9;            // nt*36 + ks
    const int nt   = t9 / 36;
    const int ks   = t9 - nt * 36;
    const int co   = nt * 32 + (lane & 31);
    const int kp   = ks * 16 + (lane >> 5) * 8 + e;
    int c, t;
    if (kp < 512) { const int rc = kp >> 3; t = kp & 7; c = ((rc & 7) << 3) | (rc >> 3); }
    else          { c = kp - 512; t = 8; }
    Wb[i] = f2bf(Wg[co * K_ + c * 9 + t]);
}

__global__ __launch_bounds__(512, 4) void sconv_mfma(
    const float* __restrict__ x,
    const float* __restrict__ Coef,
    const ushort* __restrict__ Wb,     // bf16 bits, repacked (see above)
    const float* __restrict__ bias,
    float* __restrict__ out)
{
    __shared__ __align__(16) ushort Zl[MT * SROW];   // 74752 B -> 2 blocks/CU

    const int tid = threadIdx.x;
    const int bx  = blockIdx.x;
    const int wq  = bx & 7;            // 16-wide w slice
    const int hq  = (bx >> 3) & 31;    // h quad index
    const int b   = bx >> 8;
    const int w0  = wq * 16;
    const int h0  = hq * 4;

    const int wave = tid >> 6;
    const int lane = tid & 63;
    const int mt   = wave >> 2;        // m-tile: Z rows mt*32..+31
    const int nt   = wave & 3;         // n-tile: co nt*32..+31
    const int r31  = lane & 31;
    const int u    = lane >> 5;
    const ushort* bptr = Wb + ((size_t)(nt * 36) * 64 + lane) * 8;

    // ---- Phase A: z for 64 c x (4h x 16w); 2w x 4h sites per thread ----
    {
        const int j  = (tid >> 3) & 7;
        const int c  = wave + 8 * j;           // rho(c) = 8*wave + j
        const int pw = tid & 7;                // 8 w-pairs
        const int w  = w0 + pw * 2;
        const float* xb = x + ((size_t)(b * C_ + c)) * (H_ * W_);

        // 6 rows x 4 cols of padded input (covers 2w x 4h sites' patches)
        float r[6][4];
        const bool interior = (h0 >= 4) && (h0 <= 120) && (w0 >= 16) && (w0 <= 96);
        if (interior) {                        // block-uniform: scalar branch
            const float* bp = xb + (h0 - 1) * W_ + (w - 1);
            #pragma unroll
            for (int dy = 0; dy < 6; ++dy) {
                float4 v; __builtin_memcpy(&v, bp + dy * W_, 16);  // dwordx4 @4B align
                r[dy][0] = v.x; r[dy][1] = v.y; r[dy][2] = v.z; r[dy][3] = v.w;
            }
        } else {
            // branch-free clamped loads + selects (no per-lane divergence)
            const int wm = w - 1;
            const int wc = min(max(wm, 0), W_ - 4);
            const int s  = wm - wc;            // -1 (left pad), 0, +1 (right pad)
            #pragma unroll
            for (int dy = 0; dy < 6; ++dy) {
                const int hy  = h0 + dy - 1;
                const bool hok = (unsigned)hy < (unsigned)H_;
                const int hc  = min(max(hy, 0), H_ - 1);
                float4 v; __builtin_memcpy(&v, xb + hc * W_ + wc, 16);
                const float rr0 = (s < 0) ? 0.f : ((s > 0) ? v.y : v.x);
                const float rr1 = (s < 0) ? v.x : ((s > 0) ? v.z : v.y);
                const float rr2 = (s < 0) ? v.y : ((s > 0) ? v.w : v.z);
                const float rr3 = (s < 0) ? v.z : ((s > 0) ? 0.f : v.w);
                r[dy][0] = hok ? rr0 : 0.f;
                r[dy][1] = hok ? rr1 : 0.f;
                r[dy][2] = hok ? rr2 : 0.f;
                r[dy][3] = hok ? rr3 : 0.f;
            }
        }

        const int rcb  = (wave * 8 + j) << 4;  // rho(c)*16 : byte offset of granule
        const int tailb = 1024 + 2 * c;        // byte offset of t=8 element
        #pragma unroll
        for (int hl = 0; hl < 4; ++hl) {       // adjacent h-sites share rows
            f32x2 p2[9];
            #pragma unroll
            for (int dy = 0; dy < 3; ++dy)
                #pragma unroll
                for (int dx = 0; dx < 3; ++dx)
                    p2[dy * 3 + dx] = (f32x2){ r[hl + dy][dx], r[hl + dy][dx + 1] };

            // y_i for i in {0,1,2,3,5,6,7,8}; Coef via uniform (scalar) loads
            f32x2 v2[8];
            #pragma unroll
            for (int ii = 0; ii < 8; ++ii) {
                const int i = ii + (ii >> 2);
                f32x2 acc = p2[0] * Coef[i * 9];
                #pragma unroll
                for (int jj = 1; jj < 9; ++jj) acc += p2[jj] * Coef[i * 9 + jj];
                v2[ii] = acc;
            }

            // Batcher odd-even mergesort, 8 elems, ascending (19 comparators)
            cswap2(v2[0],v2[1]); cswap2(v2[2],v2[3]); cswap2(v2[4],v2[5]); cswap2(v2[6],v2[7]);
            cswap2(v2[0],v2[2]); cswap2(v2[1],v2[3]); cswap2(v2[4],v2[6]); cswap2(v2[5],v2[7]);
            cswap2(v2[1],v2[2]); cswap2(v2[5],v2[6]);
            cswap2(v2[0],v2[4]); cswap2(v2[1],v2[5]); cswap2(v2[2],v2[6]); cswap2(v2[3],v2[7]);
            cswap2(v2[2],v2[4]); cswap2(v2[3],v2[5]);
            cswap2(v2[1],v2[2]); cswap2(v2[3],v2[4]); cswap2(v2[5],v2[6]);

            // z order: s0 s1 s2 s3 center s4 s5 s6 | s7 -> tail
            f32x2 z2[9] = { v2[0], v2[1], v2[2], v2[3], p2[4],
                            v2[4], v2[5], v2[6], v2[7] };

            char* zb0 = (char*)Zl + (size_t)(hl * 16 + pw * 2) * (SROW * 2);
            char* zb1 = zb0 + SROW * 2;
            uint4 q0 = make_uint4(pack2bf(z2[0][0], z2[1][0]), pack2bf(z2[2][0], z2[3][0]),
                                  pack2bf(z2[4][0], z2[5][0]), pack2bf(z2[6][0], z2[7][0]));
            uint4 q1 = make_uint4(pack2bf(z2[0][1], z2[1][1]), pack2bf(z2[2][1], z2[3][1]),
                                  pack2bf(z2[4][1], z2[5][1]), pack2bf(z2[6][1], z2[7][1]));
            *(uint4*)(zb0 + rcb) = q0;                 // one b128, conflict-free
            *(uint4*)(zb1 + rcb) = q1;
            *(ushort*)(zb0 + tailb) = f2bf(z2[8][0]);  // t=8 tail
            *(ushort*)(zb1 + tailb) = f2bf(z2[8][1]);
        }
    }

    // ---- B prefetch (independent of Phase A): hide L2 latency under barrier
    short8 bq[8];
    #pragma unroll
    for (int i = 0; i < 8; ++i) bq[i] = *(const short8*)(bptr + i * 512);

    __syncthreads();

    // ---- Phase B: 32x32x16 MFMA GEMM  out[m, n=co] = sum_k Z[m,k]W^T[n,k]
    const int arow = mt * 32 + r31;
    const char* abase = (const char*)Zl + (size_t)arow * (SROW * 2) + u * 16;

    bf16x8 aq[4];
    #pragma unroll
    for (int i = 0; i < 4; ++i)
        aq[i] = *(const bf16x8*)(abase + i * 32);

    f32x16 acc = {};

    #pragma unroll
    for (int ks = 0; ks < 36; ++ks) {
        bf16x8 a  = aq[ks & 3];
        short8 bb = bq[ks & 7];
        if (ks + 4 < 36)
            aq[ks & 3] = *(const bf16x8*)(abase + (ks + 4) * 32);
        if (ks + 8 < 36)
            bq[ks & 7] = *(const short8*)(bptr + (ks + 8) * 512);
        acc = __builtin_amdgcn_mfma_f32_32x32x16_bf16(a, __builtin_bit_cast(bf16x8, bb), acc, 0, 0, 0);
    }

    // ---- Epilogue: D col=lane&31 -> co-local; row=(reg&3)+8*(reg>>2)+4*u
    const int co = nt * 32 + r31;
    const float bv = bias[co];
    float* obase = out + (((size_t)(b * CO_ + co)) * H_ + h0 + mt * 2) * W_ + w0;
    #pragma unroll
    for (int qq = 0; qq < 4; ++qq) {
        const int roff = qq * 8 + u * 4;       // m-local base, multiple of 4
        const int hl   = roff >> 4;            // 0 or 1 within this m-tile
        const int wl   = roff & 15;            // 0,4,8,12
        float4 vv = make_float4(acc[qq*4+0] + bv, acc[qq*4+1] + bv,
                                acc[qq*4+2] + bv, acc[qq*4+3] + bv);
        *(float4*)(obase + hl * W_ + wl) = vv;
    }
}

// ---- fp32 fallback (round-1 kernel, direct W layout) if ws is too small ----
#define WT 16
__device__ __forceinline__ void cswap(float &a, float &b) {
    float lo = fminf(a, b);
    float hi = fmaxf(a, b);
    a = lo; b = hi;
}
__global__ __launch_bounds__(256) void sconv_fp32(
    const float* __restrict__ x, const float* __restrict__ Coef,
    const float* __restrict__ Wg, const float* __restrict__ bias,
    float* __restrict__ out)
{
    __shared__ float Cf[81];
    __shared__ float Zl[C_ * 9 * WT];
    const int tid = threadIdx.x;
    const int bx  = blockIdx.x;
    const int wt  = bx & 7;
    const int h   = (bx >> 3) & 127;
    const int b   = bx >> 10;
    const int w0  = wt * WT;
    if (tid < 81) Cf[tid] = Coef[tid];
    __syncthreads();
    for (int task = tid; task < C_ * WT; task += 256) {
        const int c = task >> 4, wl = task & 15, w = w0 + wl;
        const float* xb = x + (b * C_ + c) * H_ * W_;
        float p[9];
        #pragma unroll
        for (int dy = 0; dy < 3; ++dy) {
            const int hy = h + dy - 1; const bool hin = (unsigned)hy < (unsigned)H_;
            #pragma unroll
            for (int dx = 0; dx < 3; ++dx) {
                const int wx = w + dx - 1; const bool win = (unsigned)wx < (unsigned)W_;
                p[dy * 3 + dx] = (hin && win) ? xb[hy * W_ + wx] : 0.0f;
            }
        }
        float v[8];
        #pragma unroll
        for (int ii = 0; ii < 8; ++ii) {
            const int i = ii + (ii >> 2);
            float acc = 0.0f;
            #pragma unroll
            for (int j = 0; j < 9; ++j) acc = fmaf(Cf[i * 9 + j], p[j], acc);
            v[ii] = acc;
        }
        cswap(v[0], v[1]); cswap(v[2], v[3]); cswap(v[4], v[5]); cswap(v[6], v[7]);
        cswap(v[0], v[2]); cswap(v[1], v[3]); cswap(v[4], v[6]); cswap(v[5], v[7]);
        cswap(v[1], v[2]); cswap(v[5], v[6]);
        cswap(v[0], v[4]); cswap(v[1], v[5]); cswap(v[2], v[6]); cswap(v[3], v[7]);
        cswap(v[2], v[4]); cswap(v[3], v[5]);
        cswap(v[1], v[2]); cswap(v[3], v[4]); cswap(v[5], v[6]);
        const int base = c * 9 * WT + wl;
        Zl[base + 0*WT]=v[0]; Zl[base + 1*WT]=v[1]; Zl[base + 2*WT]=v[2]; Zl[base + 3*WT]=v[3];
        Zl[base + 4*WT]=p[4];
        Zl[base + 5*WT]=v[4]; Zl[base + 6*WT]=v[5]; Zl[base + 7*WT]=v[6]; Zl[base + 8*WT]=v[7];
    }
    __syncthreads();
    const int co = tid >> 1, w0l = (tid & 1) * 8;
    float acc[8];
    #pragma unroll
    for (int i = 0; i < 8; ++i) acc[i] = 0.0f;
    for (int c = 0; c < C_; ++c) {
        #pragma unroll
        for (int t = 0; t < 9; ++t) {
            const float wv = Wg[(co * C_ + c) * 9 + t];
            const float* zp = &Zl[(c * 9 + t) * WT + w0l];
            const float4 za = *(const float4*)zp;
            const float4 zb = *(const float4*)(zp + 4);
            acc[0]=fmaf(za.x,wv,acc[0]); acc[1]=fmaf(za.y,wv,acc[1]);
            acc[2]=fmaf(za.z,wv,acc[2]); acc[3]=fmaf(za.w,wv,acc[3]);
            acc[4]=fmaf(zb.x,wv,acc[4]); acc[5]=fmaf(zb.y,wv,acc[5]);
            acc[6]=fmaf(zb.z,wv,acc[6]); acc[7]=fmaf(zb.w,wv,acc[7]);
        }
    }
    const float bv = bias[co];
    float* op = out + ((b * CO_ + co) * H_ + h) * W_ + w0 + w0l;
    *(float4*)(op)     = make_float4(acc[0]+bv, acc[1]+bv, acc[2]+bv, acc[3]+bv);
    *(float4*)(op + 4) = make_float4(acc[4]+bv, acc[5]+bv, acc[6]+bv, acc[7]+bv);
}

extern "C" void kernel_launch(void* const* d_in, const int* in_sizes, int n_in,
                              void* d_out, int out_size, void* d_ws, size_t ws_size,
                              hipStream_t stream) {
    const float* x    = (const float*)d_in[0];
    const float* Coef = (const float*)d_in[1];
    const float* Wg   = (const float*)d_in[2];
    const float* bias = (const float*)d_in[3];
    float* out = (float*)d_out;

    const size_t need = (size_t)CO_ * K_ * sizeof(ushort);   // 147456 B
    if (ws_size >= need) {
        ushort* Wb = (ushort*)d_ws;
        conv_W_bf16<<<(CO_ * K_ + 255) / 256, 256, 0, stream>>>(Wg, Wb);
        sconv_mfma<<<B_ * (H_ / 4) * (W_ / 16), 512, 0, stream>>>(x, Coef, Wb, bias, out);
    } else {
        sconv_fp32<<<B_ * H_ * 8, 256, 0, stream>>>(x, Coef, Wg, bias, out);
    }
}

// Round 7
// 135.793 us; speedup vs baseline: 1.0580x; 1.0580x over previous
//
#include <hip/hip_runtime.h>
#include <hip/hip_bf16.h>

// SConv: x(8,64,128,128) f32, Coefficient(9,9), W(128,64,3,3), b(128)
// out[b,co,h,w] = sum_{c,t} z[b,c,h,w][t] * W[co,c,t] + b[co]
// z = [sorted8(y[noncenter])[0:4], center, sorted8[4:8]],
// y_i = sum_j Coefficient[i,j] * patch_j (3x3 neighborhood, zero pad 1).
//
// Round 14 (post-mortem R13 68us: conflicts/instrs were NOT the critical
// path; kernel is stall-bound at 12 waves/CU (LDS 74.7KB -> 2 blocks)):
//  - MT 64 -> 32 (2h x 16w): LDS 37376 B; __launch_bounds__(512,6) ->
//    3 blocks/CU = 24 waves/CU (2x resident waves).
//  - Phase B kh-SPLIT: M=32 is one 32x32 m-tile; 8 waves = (nt 0..3) x
//    (kh 0..1). Each wave: 18 MFMAs on its K-half. Then 2-barrier LDS
//    reduction: kh=1 writes partials into dead Zl (17-float stride,
//    conflict-minimal), kh=0 adds + epilogue. Halves per-block critical
//    path in both phases.
//  - Kept from R13: k-permuted Z layout (one ds_write_b128 + b16 tail per
//    row), SROW 584 (73 granules, %8=1 -> conflict-free b128 reads),
//    4-deep pre-barrier B prefetch, 2-deep A prefetch.
// Layouts: A row=lane&31, k=(lane>>5)*8+e; C/D col=lane&31=co,
// row=(reg&3)+8*(reg>>2)+4*(lane>>5) (m74/m101).

#define B_   8
#define C_   64
#define H_   128
#define W_   128
#define CO_  128
#define K_   576    // C_*9 = 36*16
#define MT   32     // sites per block (2h x 16w)
#define SROW 584    // LDS row stride in elements (1168 B = 73 granules)

typedef __attribute__((ext_vector_type(8)))  short  short8;
typedef __attribute__((ext_vector_type(8)))  __bf16 bf16x8;
typedef __attribute__((ext_vector_type(16))) float  f32x16;
typedef __attribute__((ext_vector_type(2)))  float  f32x2;

__device__ __forceinline__ void cswap2(f32x2 &a, f32x2 &b) {
    f32x2 lo = __builtin_elementwise_min(a, b);
    f32x2 hi = __builtin_elementwise_max(a, b);
    a = lo; b = hi;
}

__device__ __forceinline__ ushort f2bf(float f) {
    union { float f; unsigned u; } v; v.f = f;
    unsigned r = v.u + 0x7fffu + ((v.u >> 16) & 1u);  // RNE
    return (ushort)(r >> 16);
}

__device__ __forceinline__ unsigned pack2bf(float lo, float hi) {
    union { __hip_bfloat162 h; unsigned u; } cv;
    cv.h = __float22bfloat162_rn(make_float2(lo, hi));  // x->low word
    return cv.u;
}

// Repack W[co][c*9+t] f32 -> Wb[((nt*36+ks)*64+lane)*8+e] bf16 where
// co = nt*32+(lane&31), k' = ks*16+(lane>>5)*8+e, and k' decodes as:
//   k' < 512:  rc = k'>>3, t = k'&7, c = ((rc&7)<<3)|(rc>>3)   (rho inverse)
//   k' >= 512: c = k'-512, t = 8
// One contiguous 1 KB line per (nt,ks) = exactly one wave-fragment.
__global__ __launch_bounds__(256) void conv_W_bf16(const float* __restrict__ Wg,
                                                   ushort* __restrict__ Wb) {
    int i = blockIdx.x * 256 + threadIdx.x;
    if (i >= CO_ * K_) return;
    const int e    = i & 7;
    const int lane = (i >> 3) & 63;
    const int t9   = i >> 9;            // nt*36 + ks
    const int nt   = t9 / 36;
    const int ks   = t9 - nt * 36;
    const int co   = nt * 32 + (lane & 31);
    const int kp   = ks * 16 + (lane >> 5) * 8 + e;
    int c, t;
    if (kp < 512) { const int rc = kp >> 3; t = kp & 7; c = ((rc & 7) << 3) | (rc >> 3); }
    else          { c = kp - 512; t = 8; }
    Wb[i] = f2bf(Wg[co * K_ + c * 9 + t]);
}

__global__ __launch_bounds__(512, 6) void sconv_mfma(
    const float* __restrict__ x,
    const float* __restrict__ Coef,
    const ushort* __restrict__ Wb,     // bf16 bits, repacked (see above)
    const float* __restrict__ bias,
    float* __restrict__ out)
{
    __shared__ __align__(16) ushort Zl[MT * SROW];   // 37376 B -> 3 blocks/CU (VGPR-capped)

    const int tid = threadIdx.x;
    const int bx  = blockIdx.x;
    const int wq  = bx & 7;            // 16-wide w slice
    const int hp  = (bx >> 3) & 63;    // h pair index
    const int b   = bx >> 9;
    const int w0  = wq * 16;
    const int h0  = hp * 2;

    const int wave = tid >> 6;
    const int lane = tid & 63;
    const int nt   = wave & 3;         // n-tile: co nt*32..+31
    const int kh   = wave >> 2;        // K-half: ks kh*18 .. +17
    const int r31  = lane & 31;
    const int u    = lane >> 5;
    const ushort* bptr = Wb + ((size_t)(nt * 36 + kh * 18) * 64 + lane) * 8;

    // ---- Phase A: z for 64 c x (2h x 16w); 2w x 2h sites per thread ----
    {
        const int j  = (tid >> 3) & 7;
        const int c  = wave + 8 * j;           // rho(c) = 8*wave + j
        const int pw = tid & 7;                // 8 w-pairs
        const int w  = w0 + pw * 2;
        const float* xb = x + ((size_t)(b * C_ + c)) * (H_ * W_);

        // 4 rows x 4 cols of padded input (covers 2w x 2h sites' patches)
        float r[4][4];
        const bool interior = (h0 >= 2) && (h0 <= 124) && (w0 >= 16) && (w0 <= 96);
        if (interior) {                        // block-uniform: scalar branch
            const float* bp = xb + (h0 - 1) * W_ + (w - 1);
            #pragma unroll
            for (int dy = 0; dy < 4; ++dy) {
                float4 v; __builtin_memcpy(&v, bp + dy * W_, 16);  // dwordx4 @4B align
                r[dy][0] = v.x; r[dy][1] = v.y; r[dy][2] = v.z; r[dy][3] = v.w;
            }
        } else {
            // branch-free clamped loads + selects (no per-lane divergence)
            const int wm = w - 1;
            const int wc = min(max(wm, 0), W_ - 4);
            const int s  = wm - wc;            // -1 (left pad), 0, +1 (right pad)
            #pragma unroll
            for (int dy = 0; dy < 4; ++dy) {
                const int hy  = h0 + dy - 1;
                const bool hok = (unsigned)hy < (unsigned)H_;
                const int hc  = min(max(hy, 0), H_ - 1);
                float4 v; __builtin_memcpy(&v, xb + hc * W_ + wc, 16);
                const float rr0 = (s < 0) ? 0.f : ((s > 0) ? v.y : v.x);
                const float rr1 = (s < 0) ? v.x : ((s > 0) ? v.z : v.y);
                const float rr2 = (s < 0) ? v.y : ((s > 0) ? v.w : v.z);
                const float rr3 = (s < 0) ? v.z : ((s > 0) ? 0.f : v.w);
                r[dy][0] = hok ? rr0 : 0.f;
                r[dy][1] = hok ? rr1 : 0.f;
                r[dy][2] = hok ? rr2 : 0.f;
                r[dy][3] = hok ? rr3 : 0.f;
            }
        }

        const int rcb  = (wave * 8 + j) << 4;  // rho(c)*16 : byte offset of granule
        const int tailb = 1024 + 2 * c;        // byte offset of t=8 element
        #pragma unroll
        for (int hl = 0; hl < 2; ++hl) {       // adjacent h-sites share rows
            f32x2 p2[9];
            #pragma unroll
            for (int dy = 0; dy < 3; ++dy)
                #pragma unroll
                for (int dx = 0; dx < 3; ++dx)
                    p2[dy * 3 + dx] = (f32x2){ r[hl + dy][dx], r[hl + dy][dx + 1] };

            // y_i for i in {0,1,2,3,5,6,7,8}; Coef via uniform (scalar) loads
            f32x2 v2[8];
            #pragma unroll
            for (int ii = 0; ii < 8; ++ii) {
                const int i = ii + (ii >> 2);
                f32x2 acc = p2[0] * Coef[i * 9];
                #pragma unroll
                for (int jj = 1; jj < 9; ++jj) acc += p2[jj] * Coef[i * 9 + jj];
                v2[ii] = acc;
            }

            // Batcher odd-even mergesort, 8 elems, ascending (19 comparators)
            cswap2(v2[0],v2[1]); cswap2(v2[2],v2[3]); cswap2(v2[4],v2[5]); cswap2(v2[6],v2[7]);
            cswap2(v2[0],v2[2]); cswap2(v2[1],v2[3]); cswap2(v2[4],v2[6]); cswap2(v2[5],v2[7]);
            cswap2(v2[1],v2[2]); cswap2(v2[5],v2[6]);
            cswap2(v2[0],v2[4]); cswap2(v2[1],v2[5]); cswap2(v2[2],v2[6]); cswap2(v2[3],v2[7]);
            cswap2(v2[2],v2[4]); cswap2(v2[3],v2[5]);
            cswap2(v2[1],v2[2]); cswap2(v2[3],v2[4]); cswap2(v2[5],v2[6]);

            // z order: s0 s1 s2 s3 center s4 s5 s6 | s7 -> tail
            f32x2 z2[9] = { v2[0], v2[1], v2[2], v2[3], p2[4],
                            v2[4], v2[5], v2[6], v2[7] };

            char* zb0 = (char*)Zl + (size_t)(hl * 16 + pw * 2) * (SROW * 2);
            char* zb1 = zb0 + SROW * 2;
            uint4 q0 = make_uint4(pack2bf(z2[0][0], z2[1][0]), pack2bf(z2[2][0], z2[3][0]),
                                  pack2bf(z2[4][0], z2[5][0]), pack2bf(z2[6][0], z2[7][0]));
            uint4 q1 = make_uint4(pack2bf(z2[0][1], z2[1][1]), pack2bf(z2[2][1], z2[3][1]),
                                  pack2bf(z2[4][1], z2[5][1]), pack2bf(z2[6][1], z2[7][1]));
            *(uint4*)(zb0 + rcb) = q0;                 // one b128, conflict-free
            *(uint4*)(zb1 + rcb) = q1;
            *(ushort*)(zb0 + tailb) = f2bf(z2[8][0]);  // t=8 tail
            *(ushort*)(zb1 + tailb) = f2bf(z2[8][1]);
        }
    }

    // ---- B prefetch (independent of Phase A): hide L2 latency under barrier
    short8 bq[4];
    #pragma unroll
    for (int i = 0; i < 4; ++i) bq[i] = *(const short8*)(bptr + i * 512);

    __syncthreads();

    // ---- Phase B: 32x32x16 MFMA, K-half per wave (18 iters) ----
    const char* abase = (const char*)Zl + (size_t)r31 * (SROW * 2) + u * 16
                        + kh * 18 * 32;        // this wave's K-half base

    bf16x8 aq[2];
    aq[0] = *(const bf16x8*)(abase + 0);
    aq[1] = *(const bf16x8*)(abase + 32);

    f32x16 acc = {};

    #pragma unroll
    for (int ksl = 0; ksl < 18; ++ksl) {
        bf16x8 a  = aq[ksl & 1];
        short8 bb = bq[ksl & 3];
        if (ksl + 2 < 18)
            aq[ksl & 1] = *(const bf16x8*)(abase + (ksl + 2) * 32);
        if (ksl + 4 < 18)
            bq[ksl & 3] = *(const short8*)(bptr + (ksl + 4) * 512);
        acc = __builtin_amdgcn_mfma_f32_32x32x16_bf16(a, __builtin_bit_cast(bf16x8, bb), acc, 0, 0, 0);
    }

    // ---- kh reduction: Zl is dead now; reuse as partial-sum scratch ----
    // Layout: float slot = nt*1088 + lane*17 + i  (17-stride: conflict-minimal)
    __syncthreads();
    float* scratch = (float*)Zl;
    if (kh == 1) {
        float* sp = scratch + nt * 1088 + lane * 17;
        #pragma unroll
        for (int qq = 0; qq < 4; ++qq)
            *(float4*)(sp + qq * 4) = make_float4(acc[qq*4+0], acc[qq*4+1],
                                                  acc[qq*4+2], acc[qq*4+3]);
    }
    __syncthreads();
    if (kh == 0) {
        const float* sp = scratch + nt * 1088 + lane * 17;
        #pragma unroll
        for (int qq = 0; qq < 4; ++qq) {
            float4 pv = *(const float4*)(sp + qq * 4);
            acc[qq*4+0] += pv.x; acc[qq*4+1] += pv.y;
            acc[qq*4+2] += pv.z; acc[qq*4+3] += pv.w;
        }

        // ---- Epilogue: D col=lane&31=co-local; row=(reg&3)+8*(reg>>2)+4u=m
        const int co = nt * 32 + r31;
        const float bv = bias[co];
        float* obase = out + (((size_t)(b * CO_ + co)) * H_ + h0) * W_ + w0;
        #pragma unroll
        for (int qq = 0; qq < 4; ++qq) {
            const int roff = qq * 8 + u * 4;   // m-local base, multiple of 4
            const int hl   = roff >> 4;        // 0 or 1 (h0 / h0+1)
            const int wl   = roff & 15;        // 0,4,8,12
            float4 vv = make_float4(acc[qq*4+0] + bv, acc[qq*4+1] + bv,
                                    acc[qq*4+2] + bv, acc[qq*4+3] + bv);
            *(float4*)(obase + hl * W_ + wl) = vv;
        }
    }
}

// ---- fp32 fallback (round-1 kernel, direct W layout) if ws is too small ----
#define WT 16
__device__ __forceinline__ void cswap(float &a, float &b) {
    float lo = fminf(a, b);
    float hi = fmaxf(a, b);
    a = lo; b = hi;
}
__global__ __launch_bounds__(256) void sconv_fp32(
    const float* __restrict__ x, const float* __restrict__ Coef,
    const float* __restrict__ Wg, const float* __restrict__ bias,
    float* __restrict__ out)
{
    __shared__ float Cf[81];
    __shared__ float Zl[C_ * 9 * WT];
    const int tid = threadIdx.x;
    const int bx  = blockIdx.x;
    const int wt  = bx & 7;
    const int h   = (bx >> 3) & 127;
    const int b   = bx >> 10;
    const int w0  = wt * WT;
    if (tid < 81) Cf[tid] = Coef[tid];
    __syncthreads();
    for (int task = tid; task < C_ * WT; task += 256) {
        const int c = task >> 4, wl = task & 15, w = w0 + wl;
        const float* xb = x + (b * C_ + c) * H_ * W_;
        float p[9];
        #pragma unroll
        for (int dy = 0; dy < 3; ++dy) {
            const int hy = h + dy - 1; const bool hin = (unsigned)hy < (unsigned)H_;
            #pragma unroll
            for (int dx = 0; dx < 3; ++dx) {
                const int wx = w + dx - 1; const bool win = (unsigned)wx < (unsigned)W_;
                p[dy * 3 + dx] = (hin && win) ? xb[hy * W_ + wx] : 0.0f;
            }
        }
        float v[8];
        #pragma unroll
        for (int ii = 0; ii < 8; ++ii) {
            const int i = ii + (ii >> 2);
            float acc = 0.0f;
            #pragma unroll
            for (int j = 0; j < 9; ++j) acc = fmaf(Cf[i * 9 + j], p[j], acc);
            v[ii] = acc;
        }
        cswap(v[0], v[1]); cswap(v[2], v[3]); cswap(v[4], v[5]); cswap(v[6], v[7]);
        cswap(v[0], v[2]); cswap(v[1], v[3]); cswap(v[4], v[6]); cswap(v[5], v[7]);
        cswap(v[1], v[2]); cswap(v[5], v[6]);
        cswap(v[0], v[4]); cswap(v[1], v[5]); cswap(v[2], v[6]); cswap(v[3], v[7]);
        cswap(v[2], v[4]); cswap(v[3], v[5]);
        cswap(v[1], v[2]); cswap(v[3], v[4]); cswap(v[5], v[6]);
        const int base = c * 9 * WT + wl;
        Zl[base + 0*WT]=v[0]; Zl[base + 1*WT]=v[1]; Zl[base + 2*WT]=v[2]; Zl[base + 3*WT]=v[3];
        Zl[base + 4*WT]=p[4];
        Zl[base + 5*WT]=v[4]; Zl[base + 6*WT]=v[5]; Zl[base + 7*WT]=v[6]; Zl[base + 8*WT]=v[7];
    }
    __syncthreads();
    const int co = tid >> 1, w0l = (tid & 1) * 8;
    float acc[8];
    #pragma unroll
    for (int i = 0; i < 8; ++i) acc[i] = 0.0f;
    for (int c = 0; c < C_; ++c) {
        #pragma unroll
        for (int t = 0; t < 9; ++t) {
            const float wv = Wg[(co * C_ + c) * 9 + t];
            const float* zp = &Zl[(c * 9 + t) * WT + w0l];
            const float4 za = *(const float4*)zp;
            const float4 zb = *(const float4*)(zp + 4);
            acc[0]=fmaf(za.x,wv,acc[0]); acc[1]=fmaf(za.y,wv,acc[1]);
            acc[2]=fmaf(za.z,wv,acc[2]); acc[3]=fmaf(za.w,wv,acc[3]);
            acc[4]=fmaf(zb.x,wv,acc[4]); acc[5]=fmaf(zb.y,wv,acc[5]);
            acc[6]=fmaf(zb.z,wv,acc[6]); acc[7]=fmaf(zb.w,wv,acc[7]);
        }
    }
    const float bv = bias[co];
    float* op = out + ((b * CO_ + co) * H_ + h) * W_ + w0 + w0l;
    *(float4*)(op)     = make_float4(acc[0]+bv, acc[1]+bv, acc[2]+bv, acc[3]+bv);
    *(float4*)(op + 4) = make_float4(acc[4]+bv, acc[5]+bv, acc[6]+bv, acc[7]+bv);
}

extern "C" void kernel_launch(void* const* d_in, const int* in_sizes, int n_in,
                              void* d_out, int out_size, void* d_ws, size_t ws_size,
                              hipStream_t stream) {
    const float* x    = (const float*)d_in[0];
    const float* Coef = (const float*)d_in[1];
    const float* Wg   = (const float*)d_in[2];
    const float* bias = (const float*)d_in[3];
    float* out = (float*)d_out;

    const size_t need = (size_t)CO_ * K_ * sizeof(ushort);   // 147456 B
    if (ws_size >= need) {
        ushort* Wb = (ushort*)d_ws;
        conv_W_bf16<<<(CO_ * K_ + 255) / 256, 256, 0, stream>>>(Wg, Wb);
        sconv_mfma<<<B_ * (H_ / 2) * (W_ / 16), 512, 0, stream>>>(x, Coef, Wb, bias, out);
    } else {
        sconv_fp32<<<B_ * H_ * 8, 256, 0, stream>>>(x, Coef, Wg, bias, out);
    }
}